// Round 10
// baseline (243.958 us; speedup 1.0000x reference)
//
#include <hip/hip_runtime.h>

#define N_KSV 37248
#define N_KW  36864

typedef float f32x4 __attribute__((ext_vector_type(4)));
typedef short short8 __attribute__((ext_vector_type(8)));
typedef short short4v __attribute__((ext_vector_type(4)));
typedef __bf16 bf16x8 __attribute__((ext_vector_type(8)));

typedef const unsigned int __attribute__((address_space(1))) gu32;
typedef unsigned int __attribute__((address_space(3))) su32;

__device__ inline void gl_lds16(const void* g, void* l) {
  __builtin_amdgcn_global_load_lds((gu32*)g, (su32*)l, 16, 0, 0);
}

__device__ inline short f2bs(float f) {
  unsigned u = __builtin_bit_cast(unsigned, f);
  u += 0x7fffu + ((u >> 16) & 1u);
  return (short)(u >> 16);
}

__device__ inline f32x4 mfma16(short8 a, short8 b, f32x4 c) {
  return __builtin_amdgcn_mfma_f32_16x16x32_bf16(
      __builtin_bit_cast(bf16x8, a), __builtin_bit_cast(bf16x8, b), c, 0, 0, 0);
}

// ---------------- hypernet small chain (fp32) ----------------
__global__ void k_h0(const float* __restrict__ lat, const float* __restrict__ w,
                     const float* __restrict__ bias, float* __restrict__ h0) {
  int j = blockIdx.x * 256 + threadIdx.x;   // < 512
  int b = blockIdx.y;
  const float* lp = lat + b * 512;
  float acc = bias[j];
#pragma unroll 16
  for (int k = 0; k < 512; ++k) acc = fmaf(lp[k], w[k * 512 + j], acc);
  h0[b * 512 + j] = acc;
}

__global__ void k_t1(const float* __restrict__ h0, const float* __restrict__ w,
                     const float* __restrict__ bias, float* __restrict__ t1) {
  int j = blockIdx.x * 256 + threadIdx.x;   // < 1024
  int b = blockIdx.y;
  const float* hp = h0 + b * 512;
  float acc = bias[j];
#pragma unroll 16
  for (int k = 0; k < 512; ++k) acc = fmaf(hp[k], w[k * 1024 + j], acc);
  t1[b * 1024 + j] = fmaxf(acc, 0.f);
}

// writes hxT bf16 [16 batches][1536 k] rows 0..511 (the A operand of k5_lds)
__global__ void k_h(const float* __restrict__ h0, const float* __restrict__ t1,
                    const float* __restrict__ w, const float* __restrict__ bias,
                    float* __restrict__ h, short* __restrict__ hxT) {
  int j = blockIdx.x * 256 + threadIdx.x;   // < 512
  int b = blockIdx.y;
  const float* tp = t1 + b * 1024;
  float acc = bias[j];
#pragma unroll 16
  for (int k = 0; k < 1024; ++k) acc = fmaf(tp[k], w[k * 512 + j], acc);
  float v = acc + h0[b * 512 + j];
  h[b * 512 + j] = v;
  hxT[b * 1536 + j] = f2bs(v);
}

__global__ void k_t2(const float* __restrict__ h, const float* __restrict__ w,
                     const float* __restrict__ bias, short* __restrict__ hxT) {
  int j = blockIdx.x * 256 + threadIdx.x;   // < 1024
  int b = blockIdx.y;
  const float* hp = h + b * 512;
  float acc = bias[j];
#pragma unroll 16
  for (int k = 0; k < 512; ++k) acc = fmaf(hp[k], w[k * 1024 + j], acc);
  hxT[b * 1536 + 512 + j] = f2bs(fmaxf(acc, 0.f));   // rows 512..1535
}

// ---------------- fat GEMM via MFMA + global_load_lds staging ----------------
// ksv[16][N] = hx[16][1536] @ W[1536][N].  1 wave per 16-col panel, full K.
// Per kt (32 k-rows): DMA-stage B tile (2KB f32, 2x gl_lds16) + A tile (1KB
// bf16 from L2-resident hxT, 1x gl_lds16) into double buffers; counted
// s_waitcnt vmcnt(3) keeps next tile's loads in flight (m97/T4 pattern) --
// queue depth lives in the DMA engine, not VGPRs (which R8/R9 proved the
// compiler caps at ~2-3 loads in flight for register-target streams).
// LDS tile layouts (linear, as the DMA writes them):
//   B: [32 rows][16 f32]  (row*64B + col*4B)      bufs at 0 / 2048
//   A: [16 rows][32 bf16] (row*64B + koff*2B)     bufs at 4096 / 5120
__global__ __launch_bounds__(64) void k5_lds(
    const float* __restrict__ wsm, const float* __restrict__ w2,
    const short* __restrict__ hxT, const float* __restrict__ b2,
    float* __restrict__ ksv, short* __restrict__ kwb) {
  __shared__ __align__(16) char lds[6144];

  const int lane = threadIdx.x;
  const int col0 = blockIdx.x * 16;
  const int l15 = lane & 15;
  const int lg = lane >> 4;

  // per-lane staging source offsets (chunk c = call*64 + lane; 16B per chunk)
  const int rl = lane >> 2;          // B/A row within 16-row call window
  const size_t offB = (size_t)rl * N_KSV + col0 + (lane & 3) * 4;   // floats
  const int offA = rl * 1536 + (lane & 3) * 8;                      // shorts

#define STAGE(ktv, buf) { \
    const float* kb_ = ((ktv) < 16) ? (wsm + (size_t)((ktv) * 32) * N_KSV) \
                                    : (w2 + ((size_t)((ktv) * 32) - 512) * N_KSV); \
    gl_lds16(kb_ + offB, lds + (buf) * 2048); \
    gl_lds16(kb_ + offB + (size_t)16 * N_KSV, lds + (buf) * 2048 + 1024); \
    gl_lds16(hxT + offA + (ktv) * 32, lds + 4096 + (buf) * 1024); }

  f32x4 acc = {0.f, 0.f, 0.f, 0.f};
  const int bread = lg * 8 * 64 + l15 * 4;   // byte offset of B row lg*8, col l15
  const int aread = l15 * 64 + lg * 16;      // byte offset of A row l15, koff lg*8

#define COMPUTE(buf) { \
    short8 af_ = *reinterpret_cast<const short8*>(lds + 4096 + (buf) * 1024 + aread); \
    const char* bb_ = lds + (buf) * 2048 + bread; \
    float b0_ = *reinterpret_cast<const float*>(bb_); \
    float b1_ = *reinterpret_cast<const float*>(bb_ + 64); \
    float b2_ = *reinterpret_cast<const float*>(bb_ + 128); \
    float b3_ = *reinterpret_cast<const float*>(bb_ + 192); \
    float b4_ = *reinterpret_cast<const float*>(bb_ + 256); \
    float b5_ = *reinterpret_cast<const float*>(bb_ + 320); \
    float b6_ = *reinterpret_cast<const float*>(bb_ + 384); \
    float b7_ = *reinterpret_cast<const float*>(bb_ + 448); \
    short8 bf_; \
    bf_[0] = f2bs(b0_); bf_[1] = f2bs(b1_); bf_[2] = f2bs(b2_); bf_[3] = f2bs(b3_); \
    bf_[4] = f2bs(b4_); bf_[5] = f2bs(b5_); bf_[6] = f2bs(b6_); bf_[7] = f2bs(b7_); \
    acc = mfma16(af_, bf_, acc); }

  STAGE(0, 0);
  for (int kt = 0; kt < 47; ++kt) {
    STAGE(kt + 1, (kt + 1) & 1);
    asm volatile("s_waitcnt vmcnt(3)" ::: "memory");
    __builtin_amdgcn_sched_barrier(0);
    COMPUTE(kt & 1);
  }
  asm volatile("s_waitcnt vmcnt(0)" ::: "memory");
  __builtin_amdgcn_sched_barrier(0);
  COMPUTE(1);

#undef STAGE
#undef COMPUTE

  const int col = col0 + l15;
  const float bias = b2[col];
  const int m0 = lg * 4;
#pragma unroll
  for (int r = 0; r < 4; ++r) {
    float s = acc[r] + bias;
    ksv[(size_t)(m0 + r) * N_KSV + col] = s;
    if (col0 < N_KW)
      kwb[(size_t)(m0 + r) * N_KW + col] = f2bs(s);
  }
}

// ---------------- fused dyna block: 4 x (1x1 conv) via bf16 MFMA ----------------
__device__ inline int xT_idx(int p, int c) {
  return p * 64 + ((((c >> 3) ^ (p & 7)) << 3) | (c & 7));
}
__device__ inline int h_idx(int p, int c) {
  return p * 128 + ((((c >> 3) ^ (p & 7)) << 3) | (c & 7));
}

__global__ __launch_bounds__(256) void k_dyna(const float* __restrict__ x,
                                              const short* __restrict__ kwb,
                                              const float* __restrict__ ksv,
                                              float* __restrict__ out) {
  __shared__ __align__(16) short lds[20480];  // xT:0..4095  h1:4096..12287  h2:12288..20479
  short* xT = lds;
  short* h1 = lds + 4096;
  short* h2 = lds + 12288;

  const int tid = threadIdx.x;
  const int lane = tid & 63;
  const int w = tid >> 6;        // wave 0..3
  const int l15 = lane & 15;
  const int lg = lane >> 4;      // 0..3

  const int b = blockIdx.x >> 8;
  const int pos0 = (blockIdx.x & 255) << 6;

  const float* xb = x + ((size_t)b << 20) + pos0;           // x[b][.][pos0+.]
  const short* kw = kwb + b * N_KW;
  const float* bias = ksv + (size_t)b * N_KSV + N_KW;       // b_in | b_mid | b_out | b_sh

  // ---- stage x tile -> xT (bf16, transposed, swizzled) ----
#pragma unroll
  for (int i = 0; i < 8; ++i) {
    int p = lane;
    int cp = i * 4 + w;          // 0..31
    int c = cp * 2;
    float v0 = xb[(size_t)c * 16384 + p];
    float v1 = xb[(size_t)(c + 1) * 16384 + p];
    int idx = xT_idx(p, c);      // even; packs c, c+1
    int pk = (int)(unsigned short)f2bs(v0) | ((int)f2bs(v1) << 16);
    *reinterpret_cast<int*>(&xT[idx]) = pk;
  }
  __syncthreads();

  // ---- layer 1: h1 = relu(Kin(128x64) @ x + b_in) ----
  short8 a1[2][2];
#pragma unroll
  for (int mt = 0; mt < 2; ++mt)
#pragma unroll
    for (int kf = 0; kf < 2; ++kf)
      a1[mt][kf] = *reinterpret_cast<const short8*>(
          kw + (w * 32 + mt * 16 + l15) * 64 + kf * 32 + lg * 8);

  f32x4 zero = {0.f, 0.f, 0.f, 0.f};
  f32x4 acc1[2][4];
#pragma unroll
  for (int mt = 0; mt < 2; ++mt)
#pragma unroll
    for (int nt = 0; nt < 4; ++nt) acc1[mt][nt] = zero;

#pragma unroll
  for (int nt = 0; nt < 4; ++nt) {
    int p = nt * 16 + l15;
    short8 b0 = *reinterpret_cast<const short8*>(&xT[xT_idx(p, lg * 8)]);
    short8 b1 = *reinterpret_cast<const short8*>(&xT[xT_idx(p, 32 + lg * 8)]);
#pragma unroll
    for (int mt = 0; mt < 2; ++mt) {
      acc1[mt][nt] = mfma16(a1[mt][0], b0, acc1[mt][nt]);
      acc1[mt][nt] = mfma16(a1[mt][1], b1, acc1[mt][nt]);
    }
  }
#pragma unroll
  for (int mt = 0; mt < 2; ++mt) {
    int ch0 = w * 32 + mt * 16 + lg * 4;
    f32x4 bv = *reinterpret_cast<const f32x4*>(bias + ch0);
#pragma unroll
    for (int nt = 0; nt < 4; ++nt) {
      int p = nt * 16 + l15;
      short4v hv;
#pragma unroll
      for (int jj = 0; jj < 4; ++jj)
        hv[jj] = f2bs(fmaxf(acc1[mt][nt][jj] + bv[jj], 0.f));
      *reinterpret_cast<short4v*>(&h1[h_idx(p, ch0)]) = hv;
    }
  }
  __syncthreads();

  // ---- layer 2: h2 = relu(Kmid(128x128) @ h1 + b_mid) ----
  short8 a2[2][4];
#pragma unroll
  for (int mt = 0; mt < 2; ++mt)
#pragma unroll
    for (int kf = 0; kf < 4; ++kf)
      a2[mt][kf] = *reinterpret_cast<const short8*>(
          kw + 8192 + (w * 32 + mt * 16 + l15) * 128 + kf * 32 + lg * 8);

  f32x4 acc2[2][4];
#pragma unroll
  for (int mt = 0; mt < 2; ++mt)
#pragma unroll
    for (int nt = 0; nt < 4; ++nt) acc2[mt][nt] = zero;

#pragma unroll
  for (int nt = 0; nt < 4; ++nt) {
    int p = nt * 16 + l15;
    short8 bb[4];
#pragma unroll
    for (int kf = 0; kf < 4; ++kf)
      bb[kf] = *reinterpret_cast<const short8*>(&h1[h_idx(p, kf * 32 + lg * 8)]);
#pragma unroll
    for (int mt = 0; mt < 2; ++mt)
#pragma unroll
      for (int kf = 0; kf < 4; ++kf)
        acc2[mt][nt] = mfma16(a2[mt][kf], bb[kf], acc2[mt][nt]);
  }
#pragma unroll
  for (int mt = 0; mt < 2; ++mt) {
    int ch0 = w * 32 + mt * 16 + lg * 4;
    f32x4 bv = *reinterpret_cast<const f32x4*>(bias + 128 + ch0);
#pragma unroll
    for (int nt = 0; nt < 4; ++nt) {
      int p = nt * 16 + l15;
      short4v hv;
#pragma unroll
      for (int jj = 0; jj < 4; ++jj)
        hv[jj] = f2bs(fmaxf(acc2[mt][nt][jj] + bv[jj], 0.f));
      *reinterpret_cast<short4v*>(&h2[h_idx(p, ch0)]) = hv;
    }
  }
  __syncthreads();

  // ---- layer 3: out = Kout(64x128) @ h2 + Ksh(64x64) @ x + b_out + b_sh ----
  short8 a3[4], ash[2];
#pragma unroll
  for (int kf = 0; kf < 4; ++kf)
    a3[kf] = *reinterpret_cast<const short8*>(
        kw + 24576 + (w * 16 + l15) * 128 + kf * 32 + lg * 8);
#pragma unroll
  for (int kf = 0; kf < 2; ++kf)
    ash[kf] = *reinterpret_cast<const short8*>(
        kw + 32768 + (w * 16 + l15) * 64 + kf * 32 + lg * 8);

  int ch0 = w * 16 + lg * 4;
  f32x4 bo = *reinterpret_cast<const f32x4*>(bias + 256 + ch0);
  f32x4 bs = *reinterpret_cast<const f32x4*>(bias + 320 + ch0);

#pragma unroll
  for (int nt = 0; nt < 4; ++nt) {
    int p = nt * 16 + l15;
    f32x4 acc = zero;
#pragma unroll
    for (int kf = 0; kf < 4; ++kf) {
      short8 bb = *reinterpret_cast<const short8*>(&h2[h_idx(p, kf * 32 + lg * 8)]);
      acc = mfma16(a3[kf], bb, acc);
    }
#pragma unroll
    for (int kf = 0; kf < 2; ++kf) {
      short8 bb = *reinterpret_cast<const short8*>(&xT[xT_idx(p, kf * 32 + lg * 8)]);
      acc = mfma16(ash[kf], bb, acc);
    }
#pragma unroll
    for (int jj = 0; jj < 4; ++jj)
      out[((size_t)(b * 64 + ch0 + jj) << 14) + pos0 + p] = acc[jj] + bo[jj] + bs[jj];
  }
}

extern "C" void kernel_launch(void* const* d_in, const int* in_sizes, int n_in,
                              void* d_out, int out_size, void* d_ws, size_t ws_size,
                              hipStream_t stream) {
  const float* x    = (const float*)d_in[0];
  const float* lat  = (const float*)d_in[1];
  const float* dk_w = (const float*)d_in[2];
  const float* dk_b = (const float*)d_in[3];
  const float* l1w1 = (const float*)d_in[4];
  const float* l1b1 = (const float*)d_in[5];
  const float* l1w2 = (const float*)d_in[6];
  const float* l1b2 = (const float*)d_in[7];
  const float* l2w1 = (const float*)d_in[8];
  const float* l2b1 = (const float*)d_in[9];
  const float* l2w2 = (const float*)d_in[10];
  const float* l2b2 = (const float*)d_in[11];
  const float* l2ws = (const float*)d_in[12];
  float* out = (float*)d_out;
  float* wsf = (float*)d_ws;

  float* h0  = wsf;                          // 8192 f32
  float* t1  = wsf + 8192;                   // 16384 f32
  float* h   = wsf + 24576;                  // 8192 f32
  float* ksv = wsf + 32768;                  // 595968 f32
  short* hxT = (short*)(wsf + 628736);       // 16*1536 bf16 (A operand, [m][k])
  short* kwb = hxT + 24576;                  // 16*N_KW bf16

  k_h0<<<dim3(2, 16), 256, 0, stream>>>(lat, dk_w, dk_b, h0);
  k_t1<<<dim3(4, 16), 256, 0, stream>>>(h0, l1w1, l1b1, t1);
  k_h <<<dim3(2, 16), 256, 0, stream>>>(h0, t1, l1w2, l1b2, h, hxT);
  k_t2<<<dim3(4, 16), 256, 0, stream>>>(h, l2w1, l2b1, hxT);
  k5_lds<<<dim3(N_KSV / 16), 64, 0, stream>>>(l2ws, l2w2, hxT, l2b2, ksv, kwb);
  k_dyna<<<dim3(4096), 256, 0, stream>>>(x, kwb, ksv, out);
}

// Round 11
// 195.838 us; speedup vs baseline: 1.2457x; 1.2457x over previous
//
#include <hip/hip_runtime.h>

#define N_KSV 37248
#define N_KW  36864

typedef float f32x4 __attribute__((ext_vector_type(4)));
typedef short short8 __attribute__((ext_vector_type(8)));
typedef short short4v __attribute__((ext_vector_type(4)));
typedef __bf16 bf16x8 __attribute__((ext_vector_type(8)));

__device__ inline short f2bs(float f) {
  unsigned u = __builtin_bit_cast(unsigned, f);
  u += 0x7fffu + ((u >> 16) & 1u);
  return (short)(u >> 16);
}

__device__ inline f32x4 mfma16(short8 a, short8 b, f32x4 c) {
  return __builtin_amdgcn_mfma_f32_16x16x32_bf16(
      __builtin_bit_cast(bf16x8, a), __builtin_bit_cast(bf16x8, b), c, 0, 0, 0);
}

// ---------------- hypernet small chain (fp32) ----------------
__global__ void k_h0(const float* __restrict__ lat, const float* __restrict__ w,
                     const float* __restrict__ bias, float* __restrict__ h0) {
  int j = blockIdx.x * 256 + threadIdx.x;   // < 512
  int b = blockIdx.y;
  const float* lp = lat + b * 512;
  float acc = bias[j];
#pragma unroll 16
  for (int k = 0; k < 512; ++k) acc = fmaf(lp[k], w[k * 512 + j], acc);
  h0[b * 512 + j] = acc;
}

__global__ void k_t1(const float* __restrict__ h0, const float* __restrict__ w,
                     const float* __restrict__ bias, float* __restrict__ t1) {
  int j = blockIdx.x * 256 + threadIdx.x;   // < 1024
  int b = blockIdx.y;
  const float* hp = h0 + b * 512;
  float acc = bias[j];
#pragma unroll 16
  for (int k = 0; k < 512; ++k) acc = fmaf(hp[k], w[k * 1024 + j], acc);
  t1[b * 1024 + j] = fmaxf(acc, 0.f);
}

// writes hxT bf16 [16 batches][1536 k] rows 0..511 (the A operand of k5_mfma)
__global__ void k_h(const float* __restrict__ h0, const float* __restrict__ t1,
                    const float* __restrict__ w, const float* __restrict__ bias,
                    float* __restrict__ h, short* __restrict__ hxT) {
  int j = blockIdx.x * 256 + threadIdx.x;   // < 512
  int b = blockIdx.y;
  const float* tp = t1 + b * 1024;
  float acc = bias[j];
#pragma unroll 16
  for (int k = 0; k < 1024; ++k) acc = fmaf(tp[k], w[k * 512 + j], acc);
  float v = acc + h0[b * 512 + j];
  h[b * 512 + j] = v;
  hxT[b * 1536 + j] = f2bs(v);
}

__global__ void k_t2(const float* __restrict__ h, const float* __restrict__ w,
                     const float* __restrict__ bias, short* __restrict__ hxT) {
  int j = blockIdx.x * 256 + threadIdx.x;   // < 1024
  int b = blockIdx.y;
  const float* hp = h + b * 512;
  float acc = bias[j];
#pragma unroll 16
  for (int k = 0; k < 512; ++k) acc = fmaf(hp[k], w[k * 1024 + j], acc);
  hxT[b * 1536 + 512 + j] = f2bs(fmaxf(acc, 0.f));   // rows 512..1535
}

// ---------------- fat GEMM via MFMA (R9 variant: best measured, 97us) ----------------
#define LOADB(dst, ktv) { \
    const float* bp_ = ((ktv) < 16) ? (wsp + (size_t)((ktv) * 32) * N_KSV) \
                                    : (w2p + (size_t)((ktv) * 32 - 512) * N_KSV); \
    dst[0] = *reinterpret_cast<const f32x4*>(bp_); \
    dst[1] = *reinterpret_cast<const f32x4*>(bp_ + (size_t)1 * N_KSV); \
    dst[2] = *reinterpret_cast<const f32x4*>(bp_ + (size_t)2 * N_KSV); \
    dst[3] = *reinterpret_cast<const f32x4*>(bp_ + (size_t)3 * N_KSV); \
    dst[4] = *reinterpret_cast<const f32x4*>(bp_ + (size_t)4 * N_KSV); \
    dst[5] = *reinterpret_cast<const f32x4*>(bp_ + (size_t)5 * N_KSV); \
    dst[6] = *reinterpret_cast<const f32x4*>(bp_ + (size_t)6 * N_KSV); \
    dst[7] = *reinterpret_cast<const f32x4*>(bp_ + (size_t)7 * N_KSV); }

#define LOADA(dst, ktv) \
    dst = *reinterpret_cast<const short8*>(apb + (ktv) * 32);

#define COMPUTE(bsrc, asrc) { \
    _Pragma("unroll") \
    for (int t = 0; t < 4; ++t) { \
      short8 bf_; \
      bf_[0] = f2bs(bsrc[0][t]); bf_[1] = f2bs(bsrc[1][t]); \
      bf_[2] = f2bs(bsrc[2][t]); bf_[3] = f2bs(bsrc[3][t]); \
      bf_[4] = f2bs(bsrc[4][t]); bf_[5] = f2bs(bsrc[5][t]); \
      bf_[6] = f2bs(bsrc[6][t]); bf_[7] = f2bs(bsrc[7][t]); \
      acc[t] = mfma16(asrc, bf_, acc[t]); \
    } }

__global__ __launch_bounds__(256, 4) void k5_mfma(
    const float* __restrict__ wsm, const float* __restrict__ w2,
    const short* __restrict__ hxT, const float* __restrict__ b2,
    float* __restrict__ ksv, short* __restrict__ kwb) {
  __shared__ f32x4 red[3][64][4];
  const int tid = threadIdx.x;
  const int wv = tid >> 6;         // wave 0..3: kt in [wv*12, wv*12+12)
  const int lane = tid & 63;
  const int col0 = blockIdx.x * 64;
  const int l15 = lane & 15;
  const int lg = lane >> 4;

  const float* wsp = wsm + (size_t)(lg * 8) * N_KSV + col0 + l15 * 4;
  const float* w2p = w2 + (size_t)(lg * 8) * N_KSV + col0 + l15 * 4;
  const short* apb = hxT + l15 * 1536 + lg * 8;

  f32x4 acc[4];
#pragma unroll
  for (int t = 0; t < 4; ++t) acc[t] = (f32x4){0.f, 0.f, 0.f, 0.f};

  const int kt0 = wv * 12;
  f32x4 bA[8], bB[8];
  short8 aA, aB;
  LOADB(bA, kt0);
  LOADA(aA, kt0);

#pragma unroll
  for (int s = 0; s < 12; ++s) {
    if (s + 1 < 12) {
      if ((s & 1) == 0) {
        LOADB(bB, kt0 + s + 1);
        LOADA(aB, kt0 + s + 1);
      } else {
        LOADB(bA, kt0 + s + 1);
        LOADA(aA, kt0 + s + 1);
      }
    }
    if ((s & 1) == 0) COMPUTE(bA, aA) else COMPUTE(bB, aB)
  }

  if (wv > 0) {
#pragma unroll
    for (int t = 0; t < 4; ++t) red[wv - 1][lane][t] = acc[t];
  }
  __syncthreads();
  if (wv != 0) return;

#pragma unroll
  for (int t = 0; t < 4; ++t) {
    acc[t] += red[0][lane][t];
    acc[t] += red[1][lane][t];
    acc[t] += red[2][lane][t];
  }

  const int m0 = lg * 4;
#pragma unroll
  for (int t = 0; t < 4; ++t) {
    const int col = col0 + l15 * 4 + t;
    const float bias = b2[col];
#pragma unroll
    for (int r = 0; r < 4; ++r) {
      float s = acc[t][r] + bias;
      ksv[(size_t)(m0 + r) * N_KSV + col] = s;
      if (col < N_KW)
        kwb[(size_t)(m0 + r) * N_KW + col] = f2bs(s);
    }
  }
}

// ---------------- fused dyna block: 4 x (1x1 conv) via bf16 MFMA ----------------
// x reads / out writes are NON-TEMPORAL: both are touch-once streams (zero
// reuse); keeping them out of cache preserves L3 residency of the 229 MB
// weight stream across graph replays (k5's suspected LRU-cycle thrash).
__device__ inline int xT_idx(int p, int c) {
  return p * 64 + ((((c >> 3) ^ (p & 7)) << 3) | (c & 7));
}
__device__ inline int h_idx(int p, int c) {
  return p * 128 + ((((c >> 3) ^ (p & 7)) << 3) | (c & 7));
}

__global__ __launch_bounds__(256) void k_dyna(const float* __restrict__ x,
                                              const short* __restrict__ kwb,
                                              const float* __restrict__ ksv,
                                              float* __restrict__ out) {
  __shared__ __align__(16) short lds[20480];  // xT:0..4095  h1:4096..12287  h2:12288..20479
  short* xT = lds;
  short* h1 = lds + 4096;
  short* h2 = lds + 12288;

  const int tid = threadIdx.x;
  const int lane = tid & 63;
  const int w = tid >> 6;        // wave 0..3
  const int l15 = lane & 15;
  const int lg = lane >> 4;      // 0..3

  const int b = blockIdx.x >> 8;
  const int pos0 = (blockIdx.x & 255) << 6;

  const float* xb = x + ((size_t)b << 20) + pos0;           // x[b][.][pos0+.]
  const short* kw = kwb + b * N_KW;
  const float* bias = ksv + (size_t)b * N_KSV + N_KW;       // b_in | b_mid | b_out | b_sh

  // ---- stage x tile -> xT (bf16, transposed, swizzled; nt loads) ----
#pragma unroll
  for (int i = 0; i < 8; ++i) {
    int p = lane;
    int cp = i * 4 + w;          // 0..31
    int c = cp * 2;
    float v0 = __builtin_nontemporal_load(xb + (size_t)c * 16384 + p);
    float v1 = __builtin_nontemporal_load(xb + (size_t)(c + 1) * 16384 + p);
    int idx = xT_idx(p, c);      // even; packs c, c+1
    int pk = (int)(unsigned short)f2bs(v0) | ((int)f2bs(v1) << 16);
    *reinterpret_cast<int*>(&xT[idx]) = pk;
  }
  __syncthreads();

  // ---- layer 1: h1 = relu(Kin(128x64) @ x + b_in) ----
  short8 a1[2][2];
#pragma unroll
  for (int mt = 0; mt < 2; ++mt)
#pragma unroll
    for (int kf = 0; kf < 2; ++kf)
      a1[mt][kf] = *reinterpret_cast<const short8*>(
          kw + (w * 32 + mt * 16 + l15) * 64 + kf * 32 + lg * 8);

  f32x4 zero = {0.f, 0.f, 0.f, 0.f};
  f32x4 acc1[2][4];
#pragma unroll
  for (int mt = 0; mt < 2; ++mt)
#pragma unroll
    for (int nt = 0; nt < 4; ++nt) acc1[mt][nt] = zero;

#pragma unroll
  for (int nt = 0; nt < 4; ++nt) {
    int p = nt * 16 + l15;
    short8 b0 = *reinterpret_cast<const short8*>(&xT[xT_idx(p, lg * 8)]);
    short8 b1 = *reinterpret_cast<const short8*>(&xT[xT_idx(p, 32 + lg * 8)]);
#pragma unroll
    for (int mt = 0; mt < 2; ++mt) {
      acc1[mt][nt] = mfma16(a1[mt][0], b0, acc1[mt][nt]);
      acc1[mt][nt] = mfma16(a1[mt][1], b1, acc1[mt][nt]);
    }
  }
#pragma unroll
  for (int mt = 0; mt < 2; ++mt) {
    int ch0 = w * 32 + mt * 16 + lg * 4;
    f32x4 bv = *reinterpret_cast<const f32x4*>(bias + ch0);
#pragma unroll
    for (int nt = 0; nt < 4; ++nt) {
      int p = nt * 16 + l15;
      short4v hv;
#pragma unroll
      for (int jj = 0; jj < 4; ++jj)
        hv[jj] = f2bs(fmaxf(acc1[mt][nt][jj] + bv[jj], 0.f));
      *reinterpret_cast<short4v*>(&h1[h_idx(p, ch0)]) = hv;
    }
  }
  __syncthreads();

  // ---- layer 2: h2 = relu(Kmid(128x128) @ h1 + b_mid) ----
  short8 a2[2][4];
#pragma unroll
  for (int mt = 0; mt < 2; ++mt)
#pragma unroll
    for (int kf = 0; kf < 4; ++kf)
      a2[mt][kf] = *reinterpret_cast<const short8*>(
          kw + 8192 + (w * 32 + mt * 16 + l15) * 128 + kf * 32 + lg * 8);

  f32x4 acc2[2][4];
#pragma unroll
  for (int mt = 0; mt < 2; ++mt)
#pragma unroll
    for (int nt = 0; nt < 4; ++nt) acc2[mt][nt] = zero;

#pragma unroll
  for (int nt = 0; nt < 4; ++nt) {
    int p = nt * 16 + l15;
    short8 bb[4];
#pragma unroll
    for (int kf = 0; kf < 4; ++kf)
      bb[kf] = *reinterpret_cast<const short8*>(&h1[h_idx(p, kf * 32 + lg * 8)]);
#pragma unroll
    for (int mt = 0; mt < 2; ++mt)
#pragma unroll
      for (int kf = 0; kf < 4; ++kf)
        acc2[mt][nt] = mfma16(a2[mt][kf], bb[kf], acc2[mt][nt]);
  }
#pragma unroll
  for (int mt = 0; mt < 2; ++mt) {
    int ch0 = w * 32 + mt * 16 + lg * 4;
    f32x4 bv = *reinterpret_cast<const f32x4*>(bias + 128 + ch0);
#pragma unroll
    for (int nt = 0; nt < 4; ++nt) {
      int p = nt * 16 + l15;
      short4v hv;
#pragma unroll
      for (int jj = 0; jj < 4; ++jj)
        hv[jj] = f2bs(fmaxf(acc2[mt][nt][jj] + bv[jj], 0.f));
      *reinterpret_cast<short4v*>(&h2[h_idx(p, ch0)]) = hv;
    }
  }
  __syncthreads();

  // ---- layer 3: out = Kout(64x128) @ h2 + Ksh(64x64) @ x + b_out + b_sh ----
  short8 a3[4], ash[2];
#pragma unroll
  for (int kf = 0; kf < 4; ++kf)
    a3[kf] = *reinterpret_cast<const short8*>(
        kw + 24576 + (w * 16 + l15) * 128 + kf * 32 + lg * 8);
#pragma unroll
  for (int kf = 0; kf < 2; ++kf)
    ash[kf] = *reinterpret_cast<const short8*>(
        kw + 32768 + (w * 16 + l15) * 64 + kf * 32 + lg * 8);

  int ch0 = w * 16 + lg * 4;
  f32x4 bo = *reinterpret_cast<const f32x4*>(bias + 256 + ch0);
  f32x4 bs = *reinterpret_cast<const f32x4*>(bias + 320 + ch0);

#pragma unroll
  for (int nt = 0; nt < 4; ++nt) {
    int p = nt * 16 + l15;
    f32x4 acc = zero;
#pragma unroll
    for (int kf = 0; kf < 4; ++kf) {
      short8 bb = *reinterpret_cast<const short8*>(&h2[h_idx(p, kf * 32 + lg * 8)]);
      acc = mfma16(a3[kf], bb, acc);
    }
#pragma unroll
    for (int kf = 0; kf < 2; ++kf) {
      short8 bb = *reinterpret_cast<const short8*>(&xT[xT_idx(p, kf * 32 + lg * 8)]);
      acc = mfma16(ash[kf], bb, acc);
    }
#pragma unroll
    for (int jj = 0; jj < 4; ++jj)
      __builtin_nontemporal_store(acc[jj] + bo[jj] + bs[jj],
          out + ((size_t)(b * 64 + ch0 + jj) << 14) + pos0 + p);
  }
}

extern "C" void kernel_launch(void* const* d_in, const int* in_sizes, int n_in,
                              void* d_out, int out_size, void* d_ws, size_t ws_size,
                              hipStream_t stream) {
  const float* x    = (const float*)d_in[0];
  const float* lat  = (const float*)d_in[1];
  const float* dk_w = (const float*)d_in[2];
  const float* dk_b = (const float*)d_in[3];
  const float* l1w1 = (const float*)d_in[4];
  const float* l1b1 = (const float*)d_in[5];
  const float* l1w2 = (const float*)d_in[6];
  const float* l1b2 = (const float*)d_in[7];
  const float* l2w1 = (const float*)d_in[8];
  const float* l2b1 = (const float*)d_in[9];
  const float* l2w2 = (const float*)d_in[10];
  const float* l2b2 = (const float*)d_in[11];
  const float* l2ws = (const float*)d_in[12];
  float* out = (float*)d_out;
  float* wsf = (float*)d_ws;

  float* h0  = wsf;                          // 8192 f32
  float* t1  = wsf + 8192;                   // 16384 f32
  float* h   = wsf + 24576;                  // 8192 f32
  float* ksv = wsf + 32768;                  // 595968 f32
  short* hxT = (short*)(wsf + 628736);       // 16*1536 bf16 (A operand, [m][k])
  short* kwb = hxT + 24576;                  // 16*N_KW bf16

  k_h0<<<dim3(2, 16), 256, 0, stream>>>(lat, dk_w, dk_b, h0);
  k_t1<<<dim3(4, 16), 256, 0, stream>>>(h0, l1w1, l1b1, t1);
  k_h <<<dim3(2, 16), 256, 0, stream>>>(h0, t1, l1w2, l1b2, h, hxT);
  k_t2<<<dim3(4, 16), 256, 0, stream>>>(h, l2w1, l2b1, hxT);
  k5_mfma<<<dim3(N_KSV / 64), 256, 0, stream>>>(l2ws, l2w2, hxT, l2b2, ksv, kwb);
  k_dyna<<<dim3(4096), 256, 0, stream>>>(x, kwb, ksv, out);
}

// Round 12
// 190.260 us; speedup vs baseline: 1.2822x; 1.0293x over previous
//
#include <hip/hip_runtime.h>

#define N_KSV 37248
#define N_KW  36864

typedef float f32x4 __attribute__((ext_vector_type(4)));
typedef short short8 __attribute__((ext_vector_type(8)));
typedef short short4v __attribute__((ext_vector_type(4)));
typedef __bf16 bf16x8 __attribute__((ext_vector_type(8)));

__device__ inline short f2bs(float f) {
  unsigned u = __builtin_bit_cast(unsigned, f);
  u += 0x7fffu + ((u >> 16) & 1u);
  return (short)(u >> 16);
}

__device__ inline f32x4 mfma16(short8 a, short8 b, f32x4 c) {
  return __builtin_amdgcn_mfma_f32_16x16x32_bf16(
      __builtin_bit_cast(bf16x8, a), __builtin_bit_cast(bf16x8, b), c, 0, 0, 0);
}

// ---------------- hypernet small chain (fp32) ----------------
__global__ void k_h0(const float* __restrict__ lat, const float* __restrict__ w,
                     const float* __restrict__ bias, float* __restrict__ h0) {
  int j = blockIdx.x * 256 + threadIdx.x;   // < 512
  int b = blockIdx.y;
  const float* lp = lat + b * 512;
  float acc = bias[j];
#pragma unroll 16
  for (int k = 0; k < 512; ++k) acc = fmaf(lp[k], w[k * 512 + j], acc);
  h0[b * 512 + j] = acc;
}

__global__ void k_t1(const float* __restrict__ h0, const float* __restrict__ w,
                     const float* __restrict__ bias, float* __restrict__ t1) {
  int j = blockIdx.x * 256 + threadIdx.x;   // < 1024
  int b = blockIdx.y;
  const float* hp = h0 + b * 512;
  float acc = bias[j];
#pragma unroll 16
  for (int k = 0; k < 512; ++k) acc = fmaf(hp[k], w[k * 1024 + j], acc);
  t1[b * 1024 + j] = fmaxf(acc, 0.f);
}

// writes hxT bf16 [16 batches][1536 k] rows 0..511 (the A operand of k5_mfma)
__global__ void k_h(const float* __restrict__ h0, const float* __restrict__ t1,
                    const float* __restrict__ w, const float* __restrict__ bias,
                    float* __restrict__ h, short* __restrict__ hxT) {
  int j = blockIdx.x * 256 + threadIdx.x;   // < 512
  int b = blockIdx.y;
  const float* tp = t1 + b * 1024;
  float acc = bias[j];
#pragma unroll 16
  for (int k = 0; k < 1024; ++k) acc = fmaf(tp[k], w[k * 512 + j], acc);
  float v = acc + h0[b * 512 + j];
  h[b * 512 + j] = v;
  hxT[b * 1536 + j] = f2bs(v);
}

__global__ void k_t2(const float* __restrict__ h, const float* __restrict__ w,
                     const float* __restrict__ bias, short* __restrict__ hxT) {
  int j = blockIdx.x * 256 + threadIdx.x;   // < 1024
  int b = blockIdx.y;
  const float* hp = h + b * 512;
  float acc = bias[j];
#pragma unroll 16
  for (int k = 0; k < 512; ++k) acc = fmaf(hp[k], w[k * 1024 + j], acc);
  hxT[b * 1536 + 512 + j] = f2bs(fmaxf(acc, 0.f));   // rows 512..1535
}

// ---------------- fat GEMM via MFMA (R9 variant: best measured, 97us) ----------------
#define LOADB(dst, ktv) { \
    const float* bp_ = ((ktv) < 16) ? (wsp + (size_t)((ktv) * 32) * N_KSV) \
                                    : (w2p + (size_t)((ktv) * 32 - 512) * N_KSV); \
    dst[0] = *reinterpret_cast<const f32x4*>(bp_); \
    dst[1] = *reinterpret_cast<const f32x4*>(bp_ + (size_t)1 * N_KSV); \
    dst[2] = *reinterpret_cast<const f32x4*>(bp_ + (size_t)2 * N_KSV); \
    dst[3] = *reinterpret_cast<const f32x4*>(bp_ + (size_t)3 * N_KSV); \
    dst[4] = *reinterpret_cast<const f32x4*>(bp_ + (size_t)4 * N_KSV); \
    dst[5] = *reinterpret_cast<const f32x4*>(bp_ + (size_t)5 * N_KSV); \
    dst[6] = *reinterpret_cast<const f32x4*>(bp_ + (size_t)6 * N_KSV); \
    dst[7] = *reinterpret_cast<const f32x4*>(bp_ + (size_t)7 * N_KSV); }

#define LOADA(dst, ktv) \
    dst = *reinterpret_cast<const short8*>(apb + (ktv) * 32);

#define COMPUTE(bsrc, asrc) { \
    _Pragma("unroll") \
    for (int t = 0; t < 4; ++t) { \
      short8 bf_; \
      bf_[0] = f2bs(bsrc[0][t]); bf_[1] = f2bs(bsrc[1][t]); \
      bf_[2] = f2bs(bsrc[2][t]); bf_[3] = f2bs(bsrc[3][t]); \
      bf_[4] = f2bs(bsrc[4][t]); bf_[5] = f2bs(bsrc[5][t]); \
      bf_[6] = f2bs(bsrc[6][t]); bf_[7] = f2bs(bsrc[7][t]); \
      acc[t] = mfma16(asrc, bf_, acc[t]); \
    } }

__global__ __launch_bounds__(256, 4) void k5_mfma(
    const float* __restrict__ wsm, const float* __restrict__ w2,
    const short* __restrict__ hxT, const float* __restrict__ b2,
    float* __restrict__ ksv, short* __restrict__ kwb) {
  __shared__ f32x4 red[3][64][4];
  const int tid = threadIdx.x;
  const int wv = tid >> 6;         // wave 0..3: kt in [wv*12, wv*12+12)
  const int lane = tid & 63;
  const int col0 = blockIdx.x * 64;
  const int l15 = lane & 15;
  const int lg = lane >> 4;

  const float* wsp = wsm + (size_t)(lg * 8) * N_KSV + col0 + l15 * 4;
  const float* w2p = w2 + (size_t)(lg * 8) * N_KSV + col0 + l15 * 4;
  const short* apb = hxT + l15 * 1536 + lg * 8;

  f32x4 acc[4];
#pragma unroll
  for (int t = 0; t < 4; ++t) acc[t] = (f32x4){0.f, 0.f, 0.f, 0.f};

  const int kt0 = wv * 12;
  f32x4 bA[8], bB[8];
  short8 aA, aB;
  LOADB(bA, kt0);
  LOADA(aA, kt0);

#pragma unroll
  for (int s = 0; s < 12; ++s) {
    if (s + 1 < 12) {
      if ((s & 1) == 0) {
        LOADB(bB, kt0 + s + 1);
        LOADA(aB, kt0 + s + 1);
      } else {
        LOADB(bA, kt0 + s + 1);
        LOADA(aA, kt0 + s + 1);
      }
    }
    if ((s & 1) == 0) COMPUTE(bA, aA) else COMPUTE(bB, aB)
  }

  if (wv > 0) {
#pragma unroll
    for (int t = 0; t < 4; ++t) red[wv - 1][lane][t] = acc[t];
  }
  __syncthreads();
  if (wv != 0) return;

#pragma unroll
  for (int t = 0; t < 4; ++t) {
    acc[t] += red[0][lane][t];
    acc[t] += red[1][lane][t];
    acc[t] += red[2][lane][t];
  }

  const int m0 = lg * 4;
#pragma unroll
  for (int t = 0; t < 4; ++t) {
    const int col = col0 + l15 * 4 + t;
    const float bias = b2[col];
#pragma unroll
    for (int r = 0; r < 4; ++r) {
      float s = acc[t][r] + bias;
      ksv[(size_t)(m0 + r) * N_KSV + col] = s;
      if (col < N_KW)
        kwb[(size_t)(m0 + r) * N_KW + col] = f2bs(s);
    }
  }
}

// ---------------- fused dyna block: 4 x (1x1 conv) via bf16 MFMA ----------------
// x reads / out writes are NON-TEMPORAL: both are touch-once streams (zero
// reuse); keeping them out of cache preserves L3 residency of the 229 MB
// weight stream across graph replays (k5's suspected LRU-cycle thrash).
__device__ inline int xT_idx(int p, int c) {
  return p * 64 + ((((c >> 3) ^ (p & 7)) << 3) | (c & 7));
}
__device__ inline int h_idx(int p, int c) {
  return p * 128 + ((((c >> 3) ^ (p & 7)) << 3) | (c & 7));
}

__global__ __launch_bounds__(256) void k_dyna(const float* __restrict__ x,
                                              const short* __restrict__ kwb,
                                              const float* __restrict__ ksv,
                                              float* __restrict__ out) {
  __shared__ __align__(16) short lds[20480];  // xT:0..4095  h1:4096..12287  h2:12288..20479
  short* xT = lds;
  short* h1 = lds + 4096;
  short* h2 = lds + 12288;

  const int tid = threadIdx.x;
  const int lane = tid & 63;
  const int w = tid >> 6;        // wave 0..3
  const int l15 = lane & 15;
  const int lg = lane >> 4;      // 0..3

  const int b = blockIdx.x >> 8;
  const int pos0 = (blockIdx.x & 255) << 6;

  const float* xb = x + ((size_t)b << 20) + pos0;           // x[b][.][pos0+.]
  const short* kw = kwb + b * N_KW;
  const float* bias = ksv + (size_t)b * N_KSV + N_KW;       // b_in | b_mid | b_out | b_sh

  // ---- stage x tile -> xT (bf16, transposed, swizzled; nt loads) ----
#pragma unroll
  for (int i = 0; i < 8; ++i) {
    int p = lane;
    int cp = i * 4 + w;          // 0..31
    int c = cp * 2;
    float v0 = __builtin_nontemporal_load(xb + (size_t)c * 16384 + p);
    float v1 = __builtin_nontemporal_load(xb + (size_t)(c + 1) * 16384 + p);
    int idx = xT_idx(p, c);      // even; packs c, c+1
    int pk = (int)(unsigned short)f2bs(v0) | ((int)f2bs(v1) << 16);
    *reinterpret_cast<int*>(&xT[idx]) = pk;
  }
  __syncthreads();

  // ---- layer 1: h1 = relu(Kin(128x64) @ x + b_in) ----
  short8 a1[2][2];
#pragma unroll
  for (int mt = 0; mt < 2; ++mt)
#pragma unroll
    for (int kf = 0; kf < 2; ++kf)
      a1[mt][kf] = *reinterpret_cast<const short8*>(
          kw + (w * 32 + mt * 16 + l15) * 64 + kf * 32 + lg * 8);

  f32x4 zero = {0.f, 0.f, 0.f, 0.f};
  f32x4 acc1[2][4];
#pragma unroll
  for (int mt = 0; mt < 2; ++mt)
#pragma unroll
    for (int nt = 0; nt < 4; ++nt) acc1[mt][nt] = zero;

#pragma unroll
  for (int nt = 0; nt < 4; ++nt) {
    int p = nt * 16 + l15;
    short8 b0 = *reinterpret_cast<const short8*>(&xT[xT_idx(p, lg * 8)]);
    short8 b1 = *reinterpret_cast<const short8*>(&xT[xT_idx(p, 32 + lg * 8)]);
#pragma unroll
    for (int mt = 0; mt < 2; ++mt) {
      acc1[mt][nt] = mfma16(a1[mt][0], b0, acc1[mt][nt]);
      acc1[mt][nt] = mfma16(a1[mt][1], b1, acc1[mt][nt]);
    }
  }
#pragma unroll
  for (int mt = 0; mt < 2; ++mt) {
    int ch0 = w * 32 + mt * 16 + lg * 4;
    f32x4 bv = *reinterpret_cast<const f32x4*>(bias + ch0);
#pragma unroll
    for (int nt = 0; nt < 4; ++nt) {
      int p = nt * 16 + l15;
      short4v hv;
#pragma unroll
      for (int jj = 0; jj < 4; ++jj)
        hv[jj] = f2bs(fmaxf(acc1[mt][nt][jj] + bv[jj], 0.f));
      *reinterpret_cast<short4v*>(&h1[h_idx(p, ch0)]) = hv;
    }
  }
  __syncthreads();

  // ---- layer 2: h2 = relu(Kmid(128x128) @ h1 + b_mid) ----
  short8 a2[2][4];
#pragma unroll
  for (int mt = 0; mt < 2; ++mt)
#pragma unroll
    for (int kf = 0; kf < 4; ++kf)
      a2[mt][kf] = *reinterpret_cast<const short8*>(
          kw + 8192 + (w * 32 + mt * 16 + l15) * 128 + kf * 32 + lg * 8);

  f32x4 acc2[2][4];
#pragma unroll
  for (int mt = 0; mt < 2; ++mt)
#pragma unroll
    for (int nt = 0; nt < 4; ++nt) acc2[mt][nt] = zero;

#pragma unroll
  for (int nt = 0; nt < 4; ++nt) {
    int p = nt * 16 + l15;
    short8 bb[4];
#pragma unroll
    for (int kf = 0; kf < 4; ++kf)
      bb[kf] = *reinterpret_cast<const short8*>(&h1[h_idx(p, kf * 32 + lg * 8)]);
#pragma unroll
    for (int mt = 0; mt < 2; ++mt)
#pragma unroll
      for (int kf = 0; kf < 4; ++kf)
        acc2[mt][nt] = mfma16(a2[mt][kf], bb[kf], acc2[mt][nt]);
  }
#pragma unroll
  for (int mt = 0; mt < 2; ++mt) {
    int ch0 = w * 32 + mt * 16 + lg * 4;
    f32x4 bv = *reinterpret_cast<const f32x4*>(bias + 128 + ch0);
#pragma unroll
    for (int nt = 0; nt < 4; ++nt) {
      int p = nt * 16 + l15;
      short4v hv;
#pragma unroll
      for (int jj = 0; jj < 4; ++jj)
        hv[jj] = f2bs(fmaxf(acc2[mt][nt][jj] + bv[jj], 0.f));
      *reinterpret_cast<short4v*>(&h2[h_idx(p, ch0)]) = hv;
    }
  }
  __syncthreads();

  // ---- layer 3: out = Kout(64x128) @ h2 + Ksh(64x64) @ x + b_out + b_sh ----
  short8 a3[4], ash[2];
#pragma unroll
  for (int kf = 0; kf < 4; ++kf)
    a3[kf] = *reinterpret_cast<const short8*>(
        kw + 24576 + (w * 16 + l15) * 128 + kf * 32 + lg * 8);
#pragma unroll
  for (int kf = 0; kf < 2; ++kf)
    ash[kf] = *reinterpret_cast<const short8*>(
        kw + 32768 + (w * 16 + l15) * 64 + kf * 32 + lg * 8);

  int ch0 = w * 16 + lg * 4;
  f32x4 bo = *reinterpret_cast<const f32x4*>(bias + 256 + ch0);
  f32x4 bs = *reinterpret_cast<const f32x4*>(bias + 320 + ch0);

#pragma unroll
  for (int nt = 0; nt < 4; ++nt) {
    int p = nt * 16 + l15;
    f32x4 acc = zero;
#pragma unroll
    for (int kf = 0; kf < 4; ++kf) {
      short8 bb = *reinterpret_cast<const short8*>(&h2[h_idx(p, kf * 32 + lg * 8)]);
      acc = mfma16(a3[kf], bb, acc);
    }
#pragma unroll
    for (int kf = 0; kf < 2; ++kf) {
      short8 bb = *reinterpret_cast<const short8*>(&xT[xT_idx(p, kf * 32 + lg * 8)]);
      acc = mfma16(ash[kf], bb, acc);
    }
#pragma unroll
    for (int jj = 0; jj < 4; ++jj)
      __builtin_nontemporal_store(acc[jj] + bo[jj] + bs[jj],
          out + ((size_t)(b * 64 + ch0 + jj) << 14) + pos0 + p);
  }
}

extern "C" void kernel_launch(void* const* d_in, const int* in_sizes, int n_in,
                              void* d_out, int out_size, void* d_ws, size_t ws_size,
                              hipStream_t stream) {
  const float* x    = (const float*)d_in[0];
  const float* lat  = (const float*)d_in[1];
  const float* dk_w = (const float*)d_in[2];
  const float* dk_b = (const float*)d_in[3];
  const float* l1w1 = (const float*)d_in[4];
  const float* l1b1 = (const float*)d_in[5];
  const float* l1w2 = (const float*)d_in[6];
  const float* l1b2 = (const float*)d_in[7];
  const float* l2w1 = (const float*)d_in[8];
  const float* l2b1 = (const float*)d_in[9];
  const float* l2w2 = (const float*)d_in[10];
  const float* l2b2 = (const float*)d_in[11];
  const float* l2ws = (const float*)d_in[12];
  float* out = (float*)d_out;
  float* wsf = (float*)d_ws;

  float* h0  = wsf;                          // 8192 f32
  float* t1  = wsf + 8192;                   // 16384 f32
  float* h   = wsf + 24576;                  // 8192 f32
  float* ksv = wsf + 32768;                  // 595968 f32
  short* hxT = (short*)(wsf + 628736);       // 16*1536 bf16 (A operand, [m][k])
  short* kwb = hxT + 24576;                  // 16*N_KW bf16

  k_h0<<<dim3(2, 16), 256, 0, stream>>>(lat, dk_w, dk_b, h0);
  k_t1<<<dim3(4, 16), 256, 0, stream>>>(h0, l1w1, l1b1, t1);
  k_h <<<dim3(2, 16), 256, 0, stream>>>(h0, t1, l1w2, l1b2, h, hxT);
  k_t2<<<dim3(4, 16), 256, 0, stream>>>(h, l2w1, l2b1, hxT);
  k5_mfma<<<dim3(N_KSV / 64), 256, 0, stream>>>(l2ws, l2w2, hxT, l2b2, ksv, kwb);
  k_dyna<<<dim3(4096), 256, 0, stream>>>(x, kwb, ksv, out);
}